// Round 3
// baseline (144.562 us; speedup 1.0000x reference)
//
#include <hip/hip_runtime.h>
#include <hip/hip_fp16.h>

#define N_L 8
#define BP 4          // pairs per thread (fallback path)
#define BT 2          // triples per thread (fallback path)

#define NSEG 25
#define SEG_SHIFT 12  // 4096 rows per segment
#define SEG_ROWS 4096
#define NBINS (NSEG * NSEG)  // 625
#define BIN_NB 256           // binning blocks
#define PROC_MAXT 4          // tri entries per thread in process (capT <= 1024)

// ---------------------------------------------------------------------------
// Block (256 threads = 4 waves) sum reduction; result valid on thread 0.
// ---------------------------------------------------------------------------
__device__ __forceinline__ float block_reduce_sum(float v, float* smem) {
#pragma unroll
  for (int off = 32; off > 0; off >>= 1) v += __shfl_down(v, off, 64);
  int lane = threadIdx.x & 63;
  int wid  = threadIdx.x >> 6;
  if (lane == 0) smem[wid] = v;
  __syncthreads();
  if (threadIdx.x < 4) {
    v = smem[threadIdx.x];
    v += __shfl_down(v, 2, 64);
    v += __shfl_down(v, 1, 64);
  }
  return v;
}

// ---------------------------------------------------------------------------
// Materialize fp16 softmax table: nV x 8 half = 16B rows. Softmax in f32,
// round-to-nearest fp16 at store. Also zero-inits acc + done-counter.
// Fast path: fidx == arange(nF); fallback binary search (LDS-staged).
// ---------------------------------------------------------------------------
__global__ __launch_bounds__(256) void materialize_P16(
    const float* __restrict__ tr, const float* __restrict__ fx,
    const int* __restrict__ fidx, int nF, int nV,
    int4* __restrict__ T, double* __restrict__ acc,
    unsigned int* __restrict__ cnt) {
  __shared__ int sf[1024];
  const bool ar = (nF == 0) || (fidx[0] == 0 && fidx[nF - 1] == nF - 1);
  const bool useLds = (!ar && nF <= 1024);
  if (useLds) {
    for (int j = threadIdx.x; j < nF; j += 256) sf[j] = fidx[j];
    __syncthreads();
  }
  int v = blockIdx.x * 256 + threadIdx.x;
  if (v == 0) { acc[0] = 0.0; cnt[0] = 0u; }
  if (v >= nV) return;

  const float* src;
  if (ar) {
    src = (v < nF) ? (fx + (size_t)v * N_L) : (tr + (size_t)(v - nF) * N_L);
  } else {
    const int* __restrict__ tab = useLds ? sf : fidx;
    int lo = 0, hi = nF;
    while (lo < hi) {
      int mid = (lo + hi) >> 1;
      if (tab[mid] < v) lo = mid + 1; else hi = mid;
    }
    src = (lo < nF && tab[lo] == v) ? (fx + (size_t)lo * N_L)
                                    : (tr + (size_t)(v - lo) * N_L);
  }
  float p[N_L];
  float4 a = *(const float4*)src;
  float4 b = *(const float4*)(src + 4);
  p[0] = a.x; p[1] = a.y; p[2] = a.z; p[3] = a.w;
  p[4] = b.x; p[5] = b.y; p[6] = b.z; p[7] = b.w;
  float m = p[0];
#pragma unroll
  for (int i = 1; i < N_L; ++i) m = fmaxf(m, p[i]);
  float s = 0.f;
#pragma unroll
  for (int i = 0; i < N_L; ++i) { p[i] = __expf(p[i] - m); s += p[i]; }
  float r = 1.0f / s;
  __half2 h0 = __floats2half2_rn(p[0] * r, p[1] * r);
  __half2 h1 = __floats2half2_rn(p[2] * r, p[3] * r);
  __half2 h2 = __floats2half2_rn(p[4] * r, p[5] * r);
  __half2 h3 = __floats2half2_rn(p[6] * r, p[7] * r);
  int4 o;
  o.x = *(const int*)&h0;
  o.y = *(const int*)&h1;
  o.z = *(const int*)&h2;
  o.w = *(const int*)&h3;
  T[v] = o;
}

__device__ __forceinline__ void unpack8(int4 q, float p[N_L]) {
  float2 f;
  f = __half22float2(*(const __half2*)&q.x); p[0] = f.x; p[1] = f.y;
  f = __half22float2(*(const __half2*)&q.y); p[2] = f.x; p[3] = f.y;
  f = __half22float2(*(const __half2*)&q.z); p[4] = f.x; p[5] = f.y;
  f = __half22float2(*(const __half2*)&q.w); p[6] = f.x; p[7] = f.y;
}

// ---------------------------------------------------------------------------
// Binning: route pairs (coef -1), triple edges (coef -4, bit31 flag) and
// triples (t3 term) into (seg(a),seg(b)) bins. Per block: LDS histogram ->
// global cursor reservation -> scatter (chunk re-read is L1/L2-warm).
// Bin order within a bucket is irrelevant -> no prefix sum needed.
// Capacity-clamped writes; statistically no overflow for uniform indices.
// ---------------------------------------------------------------------------
__global__ __launch_bounds__(256) void bin_simplices(
    const int* __restrict__ s1, int nP,
    const int* __restrict__ s2, int nT,
    unsigned int* __restrict__ curE, unsigned int* __restrict__ curT,
    uint2* __restrict__ edgeBuf, int4* __restrict__ triBuf,
    int capE, int capT) {
  __shared__ unsigned int hE[NBINS], hT[NBINS], bE[NBINS], bT[NBINS];
  const int tid = threadIdx.x;
  for (int b = tid; b < NBINS; b += 256) { hE[b] = 0u; hT[b] = 0u; }
  __syncthreads();

  const int pPer = (nP + BIN_NB - 1) / BIN_NB;
  const int tPer = (nT + BIN_NB - 1) / BIN_NB;
  const int p0 = blockIdx.x * pPer, p1 = min(nP, p0 + pPer);
  const int t0 = blockIdx.x * tPer, t1 = min(nT, t0 + tPer);
  const uint2* __restrict__ s1v = (const uint2*)s1;

  // ---- count ----
  for (int i = p0 + tid; i < p1; i += 256) {
    uint2 e = s1v[i];
    int bin = (int)(e.x >> SEG_SHIFT) * NSEG + (int)(e.y >> SEG_SHIFT);
    atomicAdd(&hE[bin], 1u);
  }
  for (int i = t0 + tid; i < t1; i += 256) {
    int a = s2[3 * i], b = s2[3 * i + 1], c = s2[3 * i + 2];
    int sa = a >> SEG_SHIFT, sb = b >> SEG_SHIFT, sc = c >> SEG_SHIFT;
    atomicAdd(&hE[sa * NSEG + sb], 1u);
    atomicAdd(&hE[sa * NSEG + sc], 1u);
    atomicAdd(&hE[sb * NSEG + sc], 1u);
    atomicAdd(&hT[sa * NSEG + sb], 1u);
  }
  __syncthreads();

  // ---- reserve ranges ----
  for (int b = tid; b < NBINS; b += 256) {
    bE[b] = hE[b] ? atomicAdd(&curE[b], hE[b]) : 0u;
    bT[b] = hT[b] ? atomicAdd(&curT[b], hT[b]) : 0u;
  }
  __syncthreads();
  for (int b = tid; b < NBINS; b += 256) { hE[b] = 0u; hT[b] = 0u; }
  __syncthreads();

  // ---- scatter ----
  for (int i = p0 + tid; i < p1; i += 256) {
    uint2 e = s1v[i];
    int bin = (int)(e.x >> SEG_SHIFT) * NSEG + (int)(e.y >> SEG_SHIFT);
    unsigned int slot = bE[bin] + atomicAdd(&hE[bin], 1u);
    if (slot < (unsigned int)capE) edgeBuf[(size_t)bin * capE + slot] = e;
  }
  for (int i = t0 + tid; i < t1; i += 256) {
    int a = s2[3 * i], b = s2[3 * i + 1], c = s2[3 * i + 2];
    int sa = a >> SEG_SHIFT, sb = b >> SEG_SHIFT, sc = c >> SEG_SHIFT;
    int binAB = sa * NSEG + sb;
    int binAC = sa * NSEG + sc;
    int binBC = sb * NSEG + sc;
    unsigned int s;
    s = bE[binAB] + atomicAdd(&hE[binAB], 1u);
    if (s < (unsigned int)capE)
      edgeBuf[(size_t)binAB * capE + s] = make_uint2((unsigned int)a | 0x80000000u, (unsigned int)b);
    s = bE[binAC] + atomicAdd(&hE[binAC], 1u);
    if (s < (unsigned int)capE)
      edgeBuf[(size_t)binAC * capE + s] = make_uint2((unsigned int)a | 0x80000000u, (unsigned int)c);
    s = bE[binBC] + atomicAdd(&hE[binBC], 1u);
    if (s < (unsigned int)capE)
      edgeBuf[(size_t)binBC * capE + s] = make_uint2((unsigned int)b | 0x80000000u, (unsigned int)c);
    s = bT[binAB] + atomicAdd(&hT[binAB], 1u);
    if (s < (unsigned int)capT)
      triBuf[(size_t)binAB * capT + s] = make_int4(a, b, c, 0);
  }
}

// ---------------------------------------------------------------------------
// Process: one block per (segA,segB) bin. Stage both 4096-row segments in
// LDS (coalesced reads of the L2-resident fp16 table), prefetch t3's c-rows
// early (the only remaining random gather), then serve all dot products
// from LDS. Finalize via done-counter.
// ---------------------------------------------------------------------------
__global__ __launch_bounds__(256) void process_bins(
    const int4* __restrict__ T, int nV,
    const unsigned int* __restrict__ curE, const unsigned int* __restrict__ curT,
    const uint2* __restrict__ edgeBuf, const int4* __restrict__ triBuf,
    int capE, int capT,
    double* __restrict__ acc, unsigned int* __restrict__ cnt,
    int totalBlocks, float* __restrict__ out, double cst) {
  __shared__ int4 AS[SEG_ROWS];   // 64 KB
  __shared__ int4 BS[SEG_ROWS];   // 64 KB
  __shared__ float smem[4];
  const int tid = threadIdx.x;
  const int bin = blockIdx.x;
  const int sa = bin / NSEG, sb = bin % NSEG;
  const int aBase = sa << SEG_SHIFT, bBase = sb << SEG_SHIFT;

  for (int r = tid; r < SEG_ROWS; r += 256) {
    AS[r] = T[min(aBase + r, nV - 1)];
    BS[r] = T[min(bBase + r, nV - 1)];
  }
  __syncthreads();

  const int nE = min((int)curE[bin], capE);
  const int nTb = min((int)curT[bin], capT);

  // Issue the random c-gathers EARLY so they hide under the edge loop.
  int4 qc[PROC_MAXT];
  int ta[PROC_MAXT], tb[PROC_MAXT];
  float tw[PROC_MAXT];
#pragma unroll
  for (int u = 0; u < PROC_MAXT; ++u) {
    int j  = tid + u * 256;
    int jj = max(min(j, nTb - 1), 0);
    tw[u]  = (j < nTb) ? 1.0f : 0.0f;
    int4 t = triBuf[(size_t)bin * capT + jj];  // slot 0 may be garbage iff nTb==0 (tw=0, clamped below)
    ta[u] = t.x; tb[u] = t.y;
    qc[u] = T[max(min(t.z, nV - 1), 0)];
  }

  float local = 0.f;
  for (int j = tid; j < nE; j += 256) {
    uint2 e = edgeBuf[(size_t)bin * capE + j];
    float wgt = (e.x & 0x80000000u) ? 4.0f : 1.0f;
    int al = (int)(e.x & 0x7fffffffu) - aBase;
    int bl = (int)e.y - bBase;
    float pa[N_L], pb[N_L];
    unpack8(AS[al], pa);
    unpack8(BS[bl], pb);
    float d = 0.f;
#pragma unroll
    for (int t = 0; t < N_L; ++t) d += pa[t] * pb[t];
    local -= wgt * d;
  }

#pragma unroll
  for (int u = 0; u < PROC_MAXT; ++u) {
    int al = max(min(ta[u] - aBase, SEG_ROWS - 1), 0);
    int bl = max(min(tb[u] - bBase, SEG_ROWS - 1), 0);
    float pa[N_L], pb[N_L], pc[N_L];
    unpack8(AS[al], pa);
    unpack8(BS[bl], pb);
    unpack8(qc[u], pc);
    float t3 = 0.f;
#pragma unroll
    for (int t = 0; t < N_L; ++t) t3 += pa[t] * pb[t] * pc[t];
    local += tw[u] * (16.0f / 3.0f) * t3;
  }

  float bsum = block_reduce_sum(local, smem);
  if (tid == 0) {
    atomicAdd(acc, (double)bsum);
    __threadfence();
    unsigned int done = atomicAdd(cnt, 1u);
    if (done == (unsigned int)(totalBlocks - 1)) {
      double total = atomicAdd(acc, 0.0);  // coherent read
      out[0] = (float)(cst + total);
    }
  }
}

// ---------------------------------------------------------------------------
// Fallback 1 (proven R2): random-gather over the fp16 table.
// ---------------------------------------------------------------------------
__global__ __launch_bounds__(256) void gather_energy16(
    const int4* __restrict__ T,
    const int* __restrict__ s1, int nP,
    const int* __restrict__ s2, int nT,
    double* __restrict__ acc, unsigned int* __restrict__ cnt,
    int pairBlocks, int totalBlocks,
    float* __restrict__ out, double cst) {
  __shared__ float smem[4];
  float local = 0.f;

  if ((int)blockIdx.x < pairBlocks) {
    const unsigned long long* __restrict__ s1q = (const unsigned long long*)s1;
    int base = blockIdx.x * (256 * BP) + threadIdx.x;
    int   va[BP], vb[BP];
    float w[BP];
#pragma unroll
    for (int u = 0; u < BP; ++u) {
      int i  = base + u * 256;
      int ii = min(i, nP - 1);
      w[u]   = (i < nP) ? 1.0f : 0.0f;
      unsigned long long q = __builtin_nontemporal_load(s1q + ii);
      va[u] = (int)(unsigned int)q;
      vb[u] = (int)(q >> 32);
    }
    int4 qa[BP], qb[BP];
#pragma unroll
    for (int u = 0; u < BP; ++u) { qa[u] = T[va[u]]; qb[u] = T[vb[u]]; }
#pragma unroll
    for (int u = 0; u < BP; ++u) {
      float pa[N_L], pb[N_L];
      unpack8(qa[u], pa);
      unpack8(qb[u], pb);
      float d = 0.f;
#pragma unroll
      for (int t = 0; t < N_L; ++t) d += pa[t] * pb[t];
      local -= w[u] * d;
    }
  } else {
    int base = (blockIdx.x - pairBlocks) * (256 * BT) + threadIdx.x;
    int   v0[BT], v1[BT], v2[BT];
    float w[BT];
#pragma unroll
    for (int u = 0; u < BT; ++u) {
      int i  = base + u * 256;
      int ii = min(i, nT - 1);
      w[u]   = (i < nT) ? 1.0f : 0.0f;
      v0[u] = __builtin_nontemporal_load(s2 + 3 * ii + 0);
      v1[u] = __builtin_nontemporal_load(s2 + 3 * ii + 1);
      v2[u] = __builtin_nontemporal_load(s2 + 3 * ii + 2);
    }
    int4 qa[BT], qb[BT], qc[BT];
#pragma unroll
    for (int u = 0; u < BT; ++u) { qa[u] = T[v0[u]]; qb[u] = T[v1[u]]; qc[u] = T[v2[u]]; }
#pragma unroll
    for (int u = 0; u < BT; ++u) {
      float pa[N_L], pb[N_L], pc[N_L];
      unpack8(qa[u], pa);
      unpack8(qb[u], pb);
      unpack8(qc[u], pc);
      float d01 = 0.f, d02 = 0.f, d12 = 0.f, t3 = 0.f;
#pragma unroll
      for (int t = 0; t < N_L; ++t) {
        d01 += pa[t] * pb[t];
        d02 += pa[t] * pc[t];
        d12 += pb[t] * pc[t];
        t3  += pa[t] * pb[t] * pc[t];
      }
      local += w[u] * (-4.0f * (d01 + d02 + d12) + (16.0f / 3.0f) * t3);
    }
  }

  float bsum = block_reduce_sum(local, smem);
  if (threadIdx.x == 0) {
    atomicAdd(acc, (double)bsum);
    __threadfence();
    unsigned int done = atomicAdd(cnt, 1u);
    if (done == (unsigned int)(totalBlocks - 1)) {
      double total = atomicAdd(acc, 0.0);
      out[0] = (float)(cst + total);
    }
  }
}

// ---------------------------------------------------------------------------
// Fallback 2 (proven R1): fully fused f32 kernel, no workspace table.
// ---------------------------------------------------------------------------
__device__ __forceinline__ const float* row_ptr(
    int v, bool ar, const int* __restrict__ tab, int nF,
    const float* __restrict__ tr, const float* __restrict__ fx) {
  if (ar) {
    return (v < nF) ? (fx + (size_t)v * N_L) : (tr + (size_t)(v - nF) * N_L);
  }
  int lo = 0, hi = nF;
  while (lo < hi) {
    int mid = (lo + hi) >> 1;
    if (tab[mid] < v) lo = mid + 1; else hi = mid;
  }
  return (lo < nF && tab[lo] == v) ? (fx + (size_t)lo * N_L)
                                   : (tr + (size_t)(v - lo) * N_L);
}

__device__ __forceinline__ void softmax8(float p[N_L]) {
  float m = p[0];
#pragma unroll
  for (int i = 1; i < N_L; ++i) m = fmaxf(m, p[i]);
  float s = 0.f;
#pragma unroll
  for (int i = 0; i < N_L; ++i) { p[i] = __expf(p[i] - m); s += p[i]; }
  float r = 1.0f / s;
#pragma unroll
  for (int i = 0; i < N_L; ++i) p[i] *= r;
}

__global__ __launch_bounds__(256) void fused_energy(
    const float* __restrict__ tr, const float* __restrict__ fx,
    const int* __restrict__ fidx, int nF,
    const int* __restrict__ s1, int nP,
    const int* __restrict__ s2, int nT,
    double* __restrict__ acc, unsigned int* __restrict__ cnt,
    int pairBlocks, int totalBlocks,
    float* __restrict__ out, double cst) {
  __shared__ float smem[4];
  __shared__ int sf[1024];

  const bool ar = (nF == 0) || (fidx[0] == 0 && fidx[nF - 1] == nF - 1);
  const bool useLds = (!ar && nF <= 1024);
  if (useLds) {
    for (int j = threadIdx.x; j < nF; j += 256) sf[j] = fidx[j];
    __syncthreads();
  }
  const int* __restrict__ tab = useLds ? sf : fidx;

  float local = 0.f;

  if ((int)blockIdx.x < pairBlocks) {
    const unsigned long long* __restrict__ s1q = (const unsigned long long*)s1;
    int base = blockIdx.x * (256 * BP) + threadIdx.x;
    int   va[BP], vb[BP];
    float w[BP];
#pragma unroll
    for (int u = 0; u < BP; ++u) {
      int i  = base + u * 256;
      int ii = min(i, nP - 1);
      w[u]   = (i < nP) ? 1.0f : 0.0f;
      unsigned long long q = __builtin_nontemporal_load(s1q + ii);
      va[u] = (int)(unsigned int)q;
      vb[u] = (int)(q >> 32);
    }
    float4 a0[BP], a1[BP], b0[BP], b1[BP];
#pragma unroll
    for (int u = 0; u < BP; ++u) {
      const float4* A = (const float4*)row_ptr(va[u], ar, tab, nF, tr, fx);
      const float4* B = (const float4*)row_ptr(vb[u], ar, tab, nF, tr, fx);
      a0[u] = A[0]; a1[u] = A[1];
      b0[u] = B[0]; b1[u] = B[1];
    }
#pragma unroll
    for (int u = 0; u < BP; ++u) {
      float pa[8] = {a0[u].x, a0[u].y, a0[u].z, a0[u].w, a1[u].x, a1[u].y, a1[u].z, a1[u].w};
      float pb[8] = {b0[u].x, b0[u].y, b0[u].z, b0[u].w, b1[u].x, b1[u].y, b1[u].z, b1[u].w};
      softmax8(pa);
      softmax8(pb);
      float d = 0.f;
#pragma unroll
      for (int t = 0; t < N_L; ++t) d += pa[t] * pb[t];
      local -= w[u] * d;
    }
  } else {
    int base = (blockIdx.x - pairBlocks) * (256 * BT) + threadIdx.x;
    int   v0[BT], v1[BT], v2[BT];
    float w[BT];
#pragma unroll
    for (int u = 0; u < BT; ++u) {
      int i  = base + u * 256;
      int ii = min(i, nT - 1);
      w[u]   = (i < nT) ? 1.0f : 0.0f;
      v0[u] = __builtin_nontemporal_load(s2 + 3 * ii + 0);
      v1[u] = __builtin_nontemporal_load(s2 + 3 * ii + 1);
      v2[u] = __builtin_nontemporal_load(s2 + 3 * ii + 2);
    }
    float4 a0[BT], a1[BT], b0[BT], b1[BT], c0[BT], c1[BT];
#pragma unroll
    for (int u = 0; u < BT; ++u) {
      const float4* A = (const float4*)row_ptr(v0[u], ar, tab, nF, tr, fx);
      const float4* B = (const float4*)row_ptr(v1[u], ar, tab, nF, tr, fx);
      const float4* C = (const float4*)row_ptr(v2[u], ar, tab, nF, tr, fx);
      a0[u] = A[0]; a1[u] = A[1];
      b0[u] = B[0]; b1[u] = B[1];
      c0[u] = C[0]; c1[u] = C[1];
    }
#pragma unroll
    for (int u = 0; u < BT; ++u) {
      float pa[8] = {a0[u].x, a0[u].y, a0[u].z, a0[u].w, a1[u].x, a1[u].y, a1[u].z, a1[u].w};
      float pb[8] = {b0[u].x, b0[u].y, b0[u].z, b0[u].w, b1[u].x, b1[u].y, b1[u].z, b1[u].w};
      float pc[8] = {c0[u].x, c0[u].y, c0[u].z, c0[u].w, c1[u].x, c1[u].y, c1[u].z, c1[u].w};
      softmax8(pa);
      softmax8(pb);
      softmax8(pc);
      float d01 = 0.f, d02 = 0.f, d12 = 0.f, t3 = 0.f;
#pragma unroll
      for (int t = 0; t < N_L; ++t) {
        d01 += pa[t] * pb[t];
        d02 += pa[t] * pc[t];
        d12 += pb[t] * pc[t];
        t3  += pa[t] * pb[t] * pc[t];
      }
      local += w[u] * (-4.0f * (d01 + d02 + d12) + (16.0f / 3.0f) * t3);
    }
  }

  float bsum = block_reduce_sum(local, smem);
  if (threadIdx.x == 0) {
    atomicAdd(acc, (double)bsum);
    __threadfence();
    unsigned int done = atomicAdd(cnt, 1u);
    if (done == (unsigned int)(totalBlocks - 1)) {
      double total = atomicAdd(acc, 0.0);
      out[0] = (float)(cst + total);
    }
  }
}

extern "C" void kernel_launch(void* const* d_in, const int* in_sizes, int n_in,
                              void* d_out, int out_size, void* d_ws, size_t ws_size,
                              hipStream_t stream) {
  const float* tr   = (const float*)d_in[0];  // (N_V-N_FIXED, 8) f32
  const float* fx   = (const float*)d_in[1];  // (N_FIXED, 8) f32
  const int*   fidx = (const int*)d_in[2];    // (N_FIXED,) i32 (sorted)
  const int*   s1   = (const int*)d_in[3];    // (nP, 2) i32
  const int*   s2   = (const int*)d_in[4];    // (nT, 3) i32

  int nF = in_sizes[2];
  int nP = in_sizes[3] / 2;
  int nT = in_sizes[4] / 3;
  int nV = (in_sizes[0] + in_sizes[1]) / N_L;

  float* out = (float*)d_out;
  double cst = 2.0 * (double)nP + 8.0 * (double)nT;

  // Binned-path capacities (runtime-sized, 32-aligned, ~1.3x mean).
  int meanE = (nP + 3 * nT) / NBINS + 1;
  int capE  = ((meanE + meanE / 4 + 128) + 31) & ~31;
  int meanT = nT / NBINS + 1;
  int capT  = ((meanT + meanT / 4 + 64) + 31) & ~31;

  // Binned-path workspace layout.
  // [0,8)=acc  [16,20)=cnt  [1024,..)=curE[625]  [4096,..)=curT[625]
  // [8192,..)=T (nV*16B)  then edgeBuf, then triBuf.
  size_t offT    = 8192;
  size_t offEdge = offT + (size_t)nV * 16;
  size_t offTri  = offEdge + (size_t)NBINS * capE * 8;
  size_t needBin = offTri + (size_t)NBINS * capT * 16;

  if (ws_size >= needBin && capT <= 256 * PROC_MAXT && nV <= NSEG * SEG_ROWS) {
    double*       acc  = (double*)d_ws;
    unsigned int* cnt  = (unsigned int*)((char*)d_ws + 16);
    unsigned int* curE = (unsigned int*)((char*)d_ws + 1024);
    unsigned int* curT = (unsigned int*)((char*)d_ws + 4096);
    int4*         T    = (int4*)((char*)d_ws + offT);
    uint2*        eBuf = (uint2*)((char*)d_ws + offEdge);
    int4*         tBuf = (int4*)((char*)d_ws + offTri);

    hipMemsetAsync(d_ws, 0, 8192, stream);  // acc, cnt, cursors
    materialize_P16<<<(nV + 255) / 256, 256, 0, stream>>>(tr, fx, fidx, nF, nV, T, acc, cnt);
    bin_simplices<<<BIN_NB, 256, 0, stream>>>(s1, nP, s2, nT, curE, curT, eBuf, tBuf, capE, capT);
    process_bins<<<NBINS, 256, 0, stream>>>(T, nV, curE, curT, eBuf, tBuf, capE, capT,
                                            acc, cnt, NBINS, out, cst);
    return;
  }

  // Fallbacks: proven R2 gather path, then R1 fused path.
  double*       acc = (double*)d_ws;
  unsigned int* cnt = (unsigned int*)((char*)d_ws + 16);
  int4*         T   = (int4*)((char*)d_ws + 256);

  int pairBlocks  = (nP + 256 * BP - 1) / (256 * BP);
  int triBlocks   = (nT + 256 * BT - 1) / (256 * BT);
  int totalBlocks = pairBlocks + triBlocks;

  size_t need16 = 256 + (size_t)nV * 16;
  if (ws_size >= need16) {
    materialize_P16<<<(nV + 255) / 256, 256, 0, stream>>>(tr, fx, fidx, nF, nV, T, acc, cnt);
    gather_energy16<<<totalBlocks, 256, 0, stream>>>(
        T, s1, nP, s2, nT, acc, cnt, pairBlocks, totalBlocks, out, cst);
  } else {
    hipMemsetAsync(d_ws, 0, 32, stream);
    fused_energy<<<totalBlocks, 256, 0, stream>>>(
        tr, fx, fidx, nF, s1, nP, s2, nT, acc, cnt,
        pairBlocks, totalBlocks, out, cst);
  }
}